// Round 1
// baseline (2632.630 us; speedup 1.0000x reference)
//
#include <hip/hip_runtime.h>

// HierarchicalRNN: T=32,B=16,I=128,H=384,O=32. Persistent-register design:
// 256 blocks (1/CU) x 512 threads; block=(batch,24-row slice); plastic weights
// live in VGPRs across all 32 steps; 2 per-batch flag barriers per step.

#define NT 32
#define NBATCH 16
#define DI 128
#define DH 384
#define DOUT 32
#define KBLK 16   // blocks per batch

__device__ __forceinline__ float retanh_f(float z) {
  z = fmaxf(z, 0.0f);
  float e = __expf(-2.0f * z);
  return (1.0f - e) / (1.0f + e);
}

__device__ __forceinline__ float ald(const float* p) {
  return __hip_atomic_load(p, __ATOMIC_RELAXED, __HIP_MEMORY_SCOPE_AGENT);
}
__device__ __forceinline__ void ast(float* p, float v) {
  __hip_atomic_store(p, v, __ATOMIC_RELAXED, __HIP_MEMORY_SCOPE_AGENT);
}

__global__ void hrnn_init(int* flags) {
  int i = blockIdx.x * blockDim.x + threadIdx.x;
  if (i < 2 * NT * NBATCH) flags[i] = 0;
}

__global__ __launch_bounds__(512, 2) void hrnn(
    const float* __restrict__ x, const float* __restrict__ Rs,
    const float* __restrict__ Wx, const float* __restrict__ Wc, const float* __restrict__ bc,
    const float* __restrict__ Wch, const float* __restrict__ Whh, const float* __restrict__ bh,
    const float* __restrict__ Wo, const float* __restrict__ Wa, const float* __restrict__ ba,
    const float* __restrict__ kap, float* __restrict__ out,
    int* __restrict__ flags, float* __restrict__ comm) {
  const int tid  = threadIdx.x;
  const int lane = tid & 63;
  const int wv   = tid >> 6;
  const int bid  = blockIdx.x;
  // group all 16 blocks of a batch on one XCD (bid%8 round-robin dispatch)
  const int b = ((bid & 7) << 1) | ((bid >> 3) & 1);
  const int k = bid >> 4;

  int* flag_noc = flags;                 // [NT][NBATCH]
  int* flag_noh = flags + NT * NBATCH;
  float* noc_buf = comm;                 // [2][NBATCH][DH]
  float* noh_buf = comm + 2 * NBATCH * DH;

  const int og0 = k * 24 + wv * 3;

  // persistent plastic weights + cached relu(W_slow) slices (registers)
  float wxc[3][2], wcc[3][6], wchv[3][5], whh[3][6];
  float rWx[3][2], rWc[3][6], rWch[3][5], rWhh[3][6];
  float sc[3], sh[3], bcr[3], bar[3], bhr[3];
  float ohr[6], ocr[6];

#pragma unroll
  for (int r = 0; r < 3; ++r) {
    const int og = og0 + r;
#pragma unroll
    for (int j = 0; j < 2; ++j) { rWx[r][j] = fmaxf(Wx[og*DI + j*64 + lane], 0.f); wxc[r][j] = 0.f; }
#pragma unroll
    for (int j = 0; j < 6; ++j) { rWc[r][j] = fmaxf(Wc[og*DH + j*64 + lane], 0.f); wcc[r][j] = 0.f; }
#pragma unroll
    for (int j = 0; j < 5; ++j) { rWch[r][j] = fmaxf(Wch[og*DH + j*64 + lane], 0.f); wchv[r][j] = 0.f; }
#pragma unroll
    for (int j = 0; j < 6; ++j) { rWhh[r][j] = fmaxf(Whh[og*DH + j*64 + lane], 0.f); whh[r][j] = 0.f; }
    sc[r] = 0.f; sh[r] = 0.f;
    bcr[r] = bc[og]; bar[r] = ba[og]; bhr[r] = bh[og];
  }
#pragma unroll
  for (int j = 0; j < 6; ++j) { ohr[j] = 0.f; ocr[j] = 0.f; }
  float kp[12];
#pragma unroll
  for (int j = 0; j < 12; ++j) kp[j] = kap[j];

  for (int t = 0; t < NT; ++t) {
    // ---------------- phase A (cell layer) ----------------
    if (t > 0) {
      if (tid == 0) {
        while (__hip_atomic_load(&flag_noh[(t-1)*NBATCH + b], __ATOMIC_ACQUIRE,
                                 __HIP_MEMORY_SCOPE_AGENT) < KBLK) {}
      }
      __syncthreads();
      const float* src = noh_buf + ((t-1)&1)*NBATCH*DH + b*DH;
#pragma unroll
      for (int j = 0; j < 6; ++j) ohr[j] = ald(src + j*64 + lane);
      if (k == 0) {  // out[t-1] = noh(t-1) @ relu(W_h2o)^T (cols>=307 masked)
        const float z4 = (lane < 51) ? ohr[4] : 0.f;
#pragma unroll
        for (int m = 0; m < 4; ++m) {
          const int o = wv*4 + m;
          float a = 0.f;
#pragma unroll
          for (int j = 0; j < 4; ++j) a += fmaxf(Wo[o*DH + j*64 + lane], 0.f) * ohr[j];
          a += fmaxf(Wo[o*DH + 256 + lane], 0.f) * z4;
#pragma unroll
          for (int mm = 1; mm <= 32; mm <<= 1) a += __shfl_xor(a, mm, 64);
          if (lane == 0) out[(t-1)*NBATCH*DOUT + b*DOUT + o] = a;
        }
      }
    }
    const float dtR = 0.02f * Rs[t*NBATCH + b];
    const float x0 = x[(t*NBATCH + b)*DI + lane];
    const float x1 = x[(t*NBATCH + b)*DI + 64 + lane];
    // column masks: boundary 307 -> j<4 full, j==4 split at lane 51, j==5 flipped/zero
    const float oh4z = (lane < 51) ? ohr[4] : 0.f;
    const float oh4s = (lane < 51) ? ohr[4] : -ohr[4];
    const float oc4s = (lane < 51) ? ocr[4] : -ocr[4];
    const float inC[6] = { ocr[0], ocr[1], ocr[2], ocr[3], oc4s, -ocr[5] };
    float nocr[3];
#pragma unroll
    for (int r = 0; r < 3; ++r) {
      const int og = og0 + r;
      const int dj = og >> 6, dl = og & 63;
      float accA = 0.f, accT = 0.f;
#pragma unroll
      for (int j = 0; j < 4; ++j) accA += fmaxf(Wa[og*DH + j*64 + lane], 0.f) * ohr[j];
      accA += fmaxf(Wa[og*DH + 256 + lane], 0.f) * oh4z;
      accT += (rWx[r][0] + wxc[r][0]) * x0;
      accT += (rWx[r][1] + wxc[r][1]) * x1;
#pragma unroll
      for (int j = 0; j < 6; ++j) {
        float term = (rWc[r][j] + wcc[r][j]) * inC[j];
        if (j == dj) term = (lane == dl) ? 0.f : term;  // remove_diag
        accT += term;
      }
#pragma unroll
      for (int mm = 1; mm <= 32; mm <<= 1) {
        accA += __shfl_xor(accA, mm, 64);
        accT += __shfl_xor(accT, mm, 64);
      }
      const float attn = retanh_f(accA + bar[r]);
      const float tic = accT + bcr[r] + attn;
      sc[r] = 0.8f*sc[r] + 0.2f*tic;
      nocr[r] = retanh_f(sc[r]);
      if (lane == 0) ast(noc_buf + (t&1)*NBATCH*DH + b*DH + og, nocr[r]);
    }
    __threadfence();
    __syncthreads();
    if (tid == 0)
      __hip_atomic_fetch_add(&flag_noc[t*NBATCH + b], 1, __ATOMIC_RELEASE, __HIP_MEMORY_SCOPE_AGENT);

    // plast wxc, wcc -- overlapped with other blocks finishing phase A
    if (t < NT-1) {
      float axc[2], bxc[2];
#pragma unroll
      for (int j = 0; j < 2; ++j) {
        const float pre = (j == 0) ? x0 : x1;
        axc[j] = dtR*kp[0]*pre; bxc[j] = dtR*(kp[1] + kp[2]*pre);
      }
      float acc_[6], bcc_[6];
#pragma unroll
      for (int j = 0; j < 6; ++j) { acc_[j] = dtR*kp[3]*ocr[j]; bcc_[j] = dtR*(kp[4] + kp[5]*ocr[j]); }
#pragma unroll
      for (int r = 0; r < 3; ++r) {
        const float post = nocr[r];
#pragma unroll
        for (int j = 0; j < 2; ++j)
          wxc[r][j] = fmaxf(fmaf(wxc[r][j], 0.98f, fmaf(bxc[j], post, axc[j])), -rWx[r][j]);
#pragma unroll
        for (int j = 0; j < 6; ++j)
          wcc[r][j] = fmaxf(fmaf(wcc[r][j], 0.98f, fmaf(bcc_[j], post, acc_[j])), -rWc[r][j]);
      }
    }

    // wait for full noc
    if (tid == 0) {
      while (__hip_atomic_load(&flag_noc[t*NBATCH + b], __ATOMIC_ACQUIRE,
                               __HIP_MEMORY_SCOPE_AGENT) < KBLK) {}
    }
    __syncthreads();
    float ncr[6];
    {
      const float* src = noc_buf + (t&1)*NBATCH*DH + b*DH;
#pragma unroll
      for (int j = 0; j < 6; ++j) ncr[j] = ald(src + j*64 + lane);
    }
    // ---------------- phase B (hidden layer) ----------------
    const float nc4z = (lane < 51) ? ncr[4] : 0.f;
    const float inH[6] = { ohr[0], ohr[1], ohr[2], ohr[3], oh4s, -ohr[5] };
    const float inN[5] = { ncr[0], ncr[1], ncr[2], ncr[3], nc4z };
    float nohr[3];
#pragma unroll
    for (int r = 0; r < 3; ++r) {
      const int og = og0 + r;
      const int dj = og >> 6, dl = og & 63;
      float acc = 0.f;
#pragma unroll
      for (int j = 0; j < 5; ++j) acc += (rWch[r][j] + wchv[r][j]) * inN[j];
#pragma unroll
      for (int j = 0; j < 6; ++j) {
        float term = (rWhh[r][j] + whh[r][j]) * inH[j];
        if (j == dj) term = (lane == dl) ? 0.f : term;
        acc += term;
      }
#pragma unroll
      for (int mm = 1; mm <= 32; mm <<= 1) acc += __shfl_xor(acc, mm, 64);
      const float tih = acc + bhr[r];
      sh[r] = 0.8f*sh[r] + 0.2f*tih;
      nohr[r] = retanh_f(sh[r]);
      if (lane == 0) ast(noh_buf + (t&1)*NBATCH*DH + b*DH + og, nohr[r]);
    }
    __threadfence();
    __syncthreads();
    if (tid == 0)
      __hip_atomic_fetch_add(&flag_noh[t*NBATCH + b], 1, __ATOMIC_RELEASE, __HIP_MEMORY_SCOPE_AGENT);

    // plast wch, whh -- overlapped
    if (t < NT-1) {
      float an_[5], bn_[5];
#pragma unroll
      for (int j = 0; j < 5; ++j) { an_[j] = dtR*kp[6]*ncr[j]; bn_[j] = dtR*(kp[7] + kp[8]*ncr[j]); }
      float ah_[6], bh_[6];
#pragma unroll
      for (int j = 0; j < 6; ++j) { ah_[j] = dtR*kp[9]*ohr[j]; bh_[j] = dtR*(kp[10] + kp[11]*ohr[j]); }
#pragma unroll
      for (int r = 0; r < 3; ++r) {
        const float post = nohr[r];
#pragma unroll
        for (int j = 0; j < 5; ++j)
          wchv[r][j] = fmaxf(fmaf(wchv[r][j], 0.98f, fmaf(bn_[j], post, an_[j])), -rWch[r][j]);
#pragma unroll
        for (int j = 0; j < 6; ++j)
          whh[r][j] = fmaxf(fmaf(whh[r][j], 0.98f, fmaf(bh_[j], post, ah_[j])), -rWhh[r][j]);
      }
    }
#pragma unroll
    for (int j = 0; j < 6; ++j) ocr[j] = ncr[j];  // oc <- noc for next step
  }

  // final output row t = NT-1
  if (k == 0) {
    if (tid == 0) {
      while (__hip_atomic_load(&flag_noh[(NT-1)*NBATCH + b], __ATOMIC_ACQUIRE,
                               __HIP_MEMORY_SCOPE_AGENT) < KBLK) {}
    }
    __syncthreads();
    const float* src = noh_buf + ((NT-1)&1)*NBATCH*DH + b*DH;
    float oh2[6];
#pragma unroll
    for (int j = 0; j < 6; ++j) oh2[j] = ald(src + j*64 + lane);
    const float z4 = (lane < 51) ? oh2[4] : 0.f;
#pragma unroll
    for (int m = 0; m < 4; ++m) {
      const int o = wv*4 + m;
      float a = 0.f;
#pragma unroll
      for (int j = 0; j < 4; ++j) a += fmaxf(Wo[o*DH + j*64 + lane], 0.f) * oh2[j];
      a += fmaxf(Wo[o*DH + 256 + lane], 0.f) * z4;
#pragma unroll
      for (int mm = 1; mm <= 32; mm <<= 1) a += __shfl_xor(a, mm, 64);
      if (lane == 0) out[(NT-1)*NBATCH*DOUT + b*DOUT + o] = a;
    }
  }
}

extern "C" void kernel_launch(void* const* d_in, const int* in_sizes, int n_in,
                              void* d_out, int out_size, void* d_ws, size_t ws_size,
                              hipStream_t stream) {
  const float* x   = (const float*)d_in[0];
  const float* Rs  = (const float*)d_in[1];
  const float* Wx  = (const float*)d_in[2];
  const float* Wc  = (const float*)d_in[3];
  const float* bc  = (const float*)d_in[4];
  const float* Wch = (const float*)d_in[5];
  const float* Whh = (const float*)d_in[6];
  const float* bh  = (const float*)d_in[7];
  const float* Wo  = (const float*)d_in[8];
  const float* Wa  = (const float*)d_in[9];
  const float* ba  = (const float*)d_in[10];
  const float* kap = (const float*)d_in[11];
  float* out = (float*)d_out;

  int* flags  = (int*)d_ws;                       // 2*32*16 ints = 4096 B
  float* comm = (float*)((char*)d_ws + 4096);     // 4*16*384 floats = 96 KiB

  hipLaunchKernelGGL(hrnn_init, dim3(2), dim3(512), 0, stream, flags);
  hipLaunchKernelGGL(hrnn, dim3(256), dim3(512), 0, stream,
                     x, Rs, Wx, Wc, bc, Wch, Whh, bh, Wo, Wa, ba, kap,
                     out, flags, comm);
}

// Round 2
// 272.907 us; speedup vs baseline: 9.6466x; 9.6466x over previous
//
#include <hip/hip_runtime.h>

// HierarchicalRNN T=32,B=16,I=128,H=384,O=32.
// Persistent-register plastic weights; fence-free dataflow sync:
// comm words are self-flagging (value+2.0, sentinel 0), t-indexed buffers,
// relaxed agent-scope atomics only. No fences, no flags, no __syncthreads.

#define NT 32
#define NBATCH 16
#define DI 128
#define DH 384
#define DOUT 32

__device__ __forceinline__ float retanh_f(float z) {
  z = fmaxf(z, 0.0f);
  float e = __expf(-2.0f * z);
  return (1.0f - e) / (1.0f + e);
}

__device__ __forceinline__ float ald(const float* p) {
  return __hip_atomic_load(p, __ATOMIC_RELAXED, __HIP_MEMORY_SCOPE_AGENT);
}
__device__ __forceinline__ void ast(float* p, float v) {
  __hip_atomic_store(p, v, __ATOMIC_RELAXED, __HIP_MEMORY_SCOPE_AGENT);
}

// Poll 6 lane-owned words (encoded v+2, sentinel 0.0); decode into arr.
__device__ __forceinline__ void gather6(const float* src, int lane, float arr[6]) {
  unsigned msk = 0x3fu;
  while (msk) {
#pragma unroll
    for (int j = 0; j < 6; ++j) {
      if (msk & (1u << j)) {
        float v = ald(src + j * 64 + lane);
        if (v != 0.0f) { arr[j] = v - 2.0f; msk &= ~(1u << j); }
      }
    }
  }
}

__global__ __launch_bounds__(512, 2) void hrnn(
    const float* __restrict__ x, const float* __restrict__ Rs,
    const float* __restrict__ Wx, const float* __restrict__ Wc, const float* __restrict__ bc,
    const float* __restrict__ Wch, const float* __restrict__ Whh, const float* __restrict__ bh,
    const float* __restrict__ Wo, const float* __restrict__ Wa, const float* __restrict__ ba,
    const float* __restrict__ kap, float* __restrict__ out, float* __restrict__ comm) {
  const int tid  = threadIdx.x;
  const int lane = tid & 63;
  const int wv   = tid >> 6;
  const int bid  = blockIdx.x;
  // batch from low 4 bits (keeps one batch's 16 blocks on one XCD under %8 dispatch)
  const int b = ((bid & 7) << 1) | ((bid >> 3) & 1);
  const int k = bid >> 4;

  float* noc_buf = comm;                      // [NT][NBATCH][DH]
  float* noh_buf = comm + NT * NBATCH * DH;   // [NT][NBATCH][DH]

  const int og0 = k * 24 + wv * 3;
  const bool do_out = (k == 15);

  // persistent plastic weights + cached relu(W_slow) slices (all registers)
  float wxc[3][2], wcc[3][6], wchv[3][5], whh[3][6];
  float rWx[3][2], rWc[3][6], rWch[3][5], rWhh[3][6], rWa[3][5];
  float sc[3], sh[3], bcr[3], bar[3], bhr[3];
  float ohr[6], ocr[6];
  float rWo[4][5];

#pragma unroll
  for (int r = 0; r < 3; ++r) {
    const int og = og0 + r;
#pragma unroll
    for (int j = 0; j < 2; ++j) { rWx[r][j] = fmaxf(Wx[og*DI + j*64 + lane], 0.f); wxc[r][j] = 0.f; }
#pragma unroll
    for (int j = 0; j < 6; ++j) { rWc[r][j] = fmaxf(Wc[og*DH + j*64 + lane], 0.f); wcc[r][j] = 0.f; }
#pragma unroll
    for (int j = 0; j < 5; ++j) { rWch[r][j] = fmaxf(Wch[og*DH + j*64 + lane], 0.f); wchv[r][j] = 0.f; }
#pragma unroll
    for (int j = 0; j < 6; ++j) { rWhh[r][j] = fmaxf(Whh[og*DH + j*64 + lane], 0.f); whh[r][j] = 0.f; }
#pragma unroll
    for (int j = 0; j < 5; ++j) {
      float w = fmaxf(Wa[og*DH + j*64 + lane], 0.f);
      rWa[r][j] = (j == 4 && lane >= 51) ? 0.f : w;   // attn mask: cols>=307 zero
    }
    sc[r] = 0.f; sh[r] = 0.f;
    bcr[r] = bc[og]; bar[r] = ba[og]; bhr[r] = bh[og];
  }
  if (do_out) {
#pragma unroll
    for (int m = 0; m < 4; ++m) {
      const int o = wv * 4 + m;
#pragma unroll
      for (int j = 0; j < 5; ++j) {
        float w = fmaxf(Wo[o*DH + j*64 + lane], 0.f);
        rWo[m][j] = (j == 4 && lane >= 51) ? 0.f : w;  // h2o mask: cols>=307 zero
      }
    }
  }
#pragma unroll
  for (int j = 0; j < 6; ++j) { ohr[j] = 0.f; ocr[j] = 0.f; }
  float kp[12];
#pragma unroll
  for (int j = 0; j < 12; ++j) kp[j] = kap[j];

  for (int t = 0; t < NT; ++t) {
    // ---- gather noh[t-1] (lane-owned cols) ----
    if (t > 0) gather6(noh_buf + (t-1)*NBATCH*DH + b*DH, lane, ohr);

    // out[t-1] (k==15 blocks; reuses the gather above, off critical path)
    if (do_out && t > 0) {
#pragma unroll
      for (int m = 0; m < 4; ++m) {
        float a = 0.f;
#pragma unroll
        for (int j = 0; j < 5; ++j) a += rWo[m][j] * ohr[j];
#pragma unroll
        for (int mm = 1; mm <= 32; mm <<= 1) a += __shfl_xor(a, mm, 64);
        if (lane == 0) out[(t-1)*NBATCH*DOUT + b*DOUT + wv*4 + m] = a;
      }
    }

    const float dtR = 0.02f * Rs[t*NBATCH + b];
    const float x0 = x[(t*NBATCH + b)*DI + lane];
    const float x1 = x[(t*NBATCH + b)*DI + 64 + lane];
    // column sign masks (boundary col 307 = j4/lane51)
    const float oh4s = (lane < 51) ? ohr[4] : -ohr[4];
    const float oc4s = (lane < 51) ? ocr[4] : -ocr[4];
    const float inC[6] = { ocr[0], ocr[1], ocr[2], ocr[3], oc4s, -ocr[5] };

    // ---------------- phase A (cell layer) ----------------
    float nocr[3];
#pragma unroll
    for (int r = 0; r < 3; ++r) {
      const int og = og0 + r;
      const int dj = og >> 6, dl = og & 63;
      float accA = 0.f, accT = 0.f;
#pragma unroll
      for (int j = 0; j < 5; ++j) accA += rWa[r][j] * ohr[j];
      accT += (rWx[r][0] + wxc[r][0]) * x0;
      accT += (rWx[r][1] + wxc[r][1]) * x1;
#pragma unroll
      for (int j = 0; j < 6; ++j) {
        float term = (rWc[r][j] + wcc[r][j]) * inC[j];
        if (j == dj) term = (lane == dl) ? 0.f : term;  // remove_diag
        accT += term;
      }
#pragma unroll
      for (int mm = 1; mm <= 32; mm <<= 1) {
        accA += __shfl_xor(accA, mm, 64);
        accT += __shfl_xor(accT, mm, 64);
      }
      const float attn = retanh_f(accA + bar[r]);
      const float tic = accT + bcr[r] + attn;
      sc[r] = 0.8f*sc[r] + 0.2f*tic;
      nocr[r] = retanh_f(sc[r]);
    }
    {  // publish 3 rows: lanes 0..2, consecutive addresses, one instruction
      float mine = (lane == 0) ? nocr[0] : (lane == 1) ? nocr[1] : nocr[2];
      if (lane < 3) ast(noc_buf + t*NBATCH*DH + b*DH + og0 + lane, mine + 2.0f);
    }

    // plast wxc, wcc (uses OLD oc) -- overlaps other blocks' phase A
    if (t < NT-1) {
      float axc[2], bxc[2];
#pragma unroll
      for (int j = 0; j < 2; ++j) {
        const float pre = (j == 0) ? x0 : x1;
        axc[j] = dtR*kp[0]*pre; bxc[j] = dtR*(kp[1] + kp[2]*pre);
      }
      float acc_[6], bcc_[6];
#pragma unroll
      for (int j = 0; j < 6; ++j) { acc_[j] = dtR*kp[3]*ocr[j]; bcc_[j] = dtR*(kp[4] + kp[5]*ocr[j]); }
#pragma unroll
      for (int r = 0; r < 3; ++r) {
        const float post = nocr[r];
#pragma unroll
        for (int j = 0; j < 2; ++j)
          wxc[r][j] = fmaxf(fmaf(wxc[r][j], 0.98f, fmaf(bxc[j], post, axc[j])), -rWx[r][j]);
#pragma unroll
        for (int j = 0; j < 6; ++j)
          wcc[r][j] = fmaxf(fmaf(wcc[r][j], 0.98f, fmaf(bcc_[j], post, acc_[j])), -rWc[r][j]);
      }
    }

    // ---- gather full-batch noc[t] (lane-owned cols) ----
    float ncr[6];
    gather6(noc_buf + t*NBATCH*DH + b*DH, lane, ncr);

    // ---------------- phase B (hidden layer) ----------------
    const float nc4z = (lane < 51) ? ncr[4] : 0.f;
    const float inH[6] = { ohr[0], ohr[1], ohr[2], ohr[3], oh4s, -ohr[5] };
    const float inN[5] = { ncr[0], ncr[1], ncr[2], ncr[3], nc4z };
    float nohr[3];
#pragma unroll
    for (int r = 0; r < 3; ++r) {
      const int og = og0 + r;
      const int dj = og >> 6, dl = og & 63;
      float acc = 0.f;
#pragma unroll
      for (int j = 0; j < 5; ++j) acc += (rWch[r][j] + wchv[r][j]) * inN[j];
#pragma unroll
      for (int j = 0; j < 6; ++j) {
        float term = (rWhh[r][j] + whh[r][j]) * inH[j];
        if (j == dj) term = (lane == dl) ? 0.f : term;
        acc += term;
      }
#pragma unroll
      for (int mm = 1; mm <= 32; mm <<= 1) acc += __shfl_xor(acc, mm, 64);
      const float tih = acc + bhr[r];
      sh[r] = 0.8f*sh[r] + 0.2f*tih;
      nohr[r] = retanh_f(sh[r]);
    }
    {
      float mine = (lane == 0) ? nohr[0] : (lane == 1) ? nohr[1] : nohr[2];
      if (lane < 3) ast(noh_buf + t*NBATCH*DH + b*DH + og0 + lane, mine + 2.0f);
    }

    // plast wch, whh (pre: new noc / old oh; post: new noh)
    if (t < NT-1) {
      float an_[5], bn_[5];
#pragma unroll
      for (int j = 0; j < 5; ++j) { an_[j] = dtR*kp[6]*ncr[j]; bn_[j] = dtR*(kp[7] + kp[8]*ncr[j]); }
      float ah_[6], bh_[6];
#pragma unroll
      for (int j = 0; j < 6; ++j) { ah_[j] = dtR*kp[9]*ohr[j]; bh_[j] = dtR*(kp[10] + kp[11]*ohr[j]); }
#pragma unroll
      for (int r = 0; r < 3; ++r) {
        const float post = nohr[r];
#pragma unroll
        for (int j = 0; j < 5; ++j)
          wchv[r][j] = fmaxf(fmaf(wchv[r][j], 0.98f, fmaf(bn_[j], post, an_[j])), -rWch[r][j]);
#pragma unroll
        for (int j = 0; j < 6; ++j)
          whh[r][j] = fmaxf(fmaf(whh[r][j], 0.98f, fmaf(bh_[j], post, ah_[j])), -rWhh[r][j]);
      }
    }
#pragma unroll
    for (int j = 0; j < 6; ++j) ocr[j] = ncr[j];  // oc <- noc
  }

  // final output row t = NT-1 (fresh gather of noh[31])
  if (do_out) {
    float oh2[6];
    gather6(noh_buf + (NT-1)*NBATCH*DH + b*DH, lane, oh2);
#pragma unroll
    for (int m = 0; m < 4; ++m) {
      float a = 0.f;
#pragma unroll
      for (int j = 0; j < 5; ++j) a += rWo[m][j] * oh2[j];
#pragma unroll
      for (int mm = 1; mm <= 32; mm <<= 1) a += __shfl_xor(a, mm, 64);
      if (lane == 0) out[(NT-1)*NBATCH*DOUT + b*DOUT + wv*4 + m] = a;
    }
  }
}

extern "C" void kernel_launch(void* const* d_in, const int* in_sizes, int n_in,
                              void* d_out, int out_size, void* d_ws, size_t ws_size,
                              hipStream_t stream) {
  const float* x   = (const float*)d_in[0];
  const float* Rs  = (const float*)d_in[1];
  const float* Wx  = (const float*)d_in[2];
  const float* Wc  = (const float*)d_in[3];
  const float* bc  = (const float*)d_in[4];
  const float* Wch = (const float*)d_in[5];
  const float* Whh = (const float*)d_in[6];
  const float* bh  = (const float*)d_in[7];
  const float* Wo  = (const float*)d_in[8];
  const float* Wa  = (const float*)d_in[9];
  const float* ba  = (const float*)d_in[10];
  const float* kap = (const float*)d_in[11];
  float* out = (float*)d_out;

  float* comm = (float*)d_ws;  // 2 * NT*NBATCH*DH floats = 1.5 MiB
  const size_t comm_bytes = (size_t)2 * NT * NBATCH * DH * sizeof(float);
  hipMemsetAsync(comm, 0, comm_bytes, stream);

  hipLaunchKernelGGL(hrnn, dim3(256), dim3(512), 0, stream,
                     x, Rs, Wx, Wc, bc, Wch, Whh, bh, Wo, Wa, ba, kap,
                     out, comm);
}